// Round 4
// baseline (1795.744 us; speedup 1.0000x reference)
//
#include <hip/hip_runtime.h>

#define BB 4
#define NN 4096
#define CC 128
#define DD 131          // 3 + 128
#define NPOINT 1024

typedef float f32x4 __attribute__((ext_vector_type(4)));

// IEEE-exact, non-fusable fp32 ops (intrinsics are immune to -ffp-contract)
__device__ __forceinline__ float fmul_(float a, float b) { return __fmul_rn(a, b); }
__device__ __forceinline__ float fadd_(float a, float b) { return __fadd_rn(a, b); }

// ---------------------------------------------------------------------------
// dist[b][i][j] = fl(fl(aa_i + aa_j) - 2*ab_ij)   (x2 exact, one rounding)
//   ab = ascending-k single-accumulator FMA chain (Eigen gebp order)
//   aa = XLA:CPU VF8-IC4 reduce. VERIFIED bit-exact (rounds 11-18, absmax 0).
// 64x64 tile, 4x4/thread, k-major LDS, two K chunks. Arithmetic order FROZEN.
// ---------------------------------------------------------------------------
__global__ __launch_bounds__(256) void dist_kernel(const float* __restrict__ points,
                                                   const float* __restrict__ features,
                                                   float* __restrict__ dist) {
    __shared__ float As[67][64];
    __shared__ float Bs[67][64];
    __shared__ float s_aai[64];
    __shared__ float s_aaj[64];

    const int b  = blockIdx.z;
    const int i0 = blockIdx.x * 64;
    const int j0 = blockIdx.y * 64;
    const int tid = threadIdx.x;
    const int r = tid & 63, g = tid >> 6;
    const int tx = tid & 15;
    const int ty = tid >> 4;

    for (int k = g; k < 64; k += 4) {
        float av, bv;
        if (k < 3) {
            av = points[((size_t)b * NN + i0 + r) * 3 + k];
            bv = points[((size_t)b * NN + j0 + r) * 3 + k];
        } else {
            const float* frow = features + ((size_t)b * CC + (k - 3)) * NN;
            av = frow[i0 + r];
            bv = frow[j0 + r];
        }
        As[k][r] = av;
        Bs[k][r] = bv;
    }
    __syncthreads();

    float ph[4][8];
    if (tid < 128) {
        const int rr = tid & 63;
        const float (*S)[64] = (tid < 64) ? As : Bs;
#pragma unroll
        for (int j = 0; j < 4; ++j)
#pragma unroll
            for (int l = 0; l < 8; ++l) {
                float x = S[8 * j + l][rr];
                ph[j][l] = fmul_(x, x);                       // it = 0
            }
#pragma unroll
        for (int j = 0; j < 4; ++j)
#pragma unroll
            for (int l = 0; l < 8; ++l) {
                float x = S[32 + 8 * j + l][rr];
                ph[j][l] = fadd_(ph[j][l], fmul_(x, x));      // it = 1
            }
    }

    float acc[4][4];
#pragma unroll
    for (int p = 0; p < 4; ++p)
#pragma unroll
        for (int q = 0; q < 4; ++q) acc[p][q] = 0.f;

#pragma unroll 4
    for (int kk = 0; kk < 64; ++kk) {
        float4 a4 = *(const float4*)&As[kk][4 * ty];
        float4 b4 = *(const float4*)&Bs[kk][4 * tx];
        const float a[4] = {a4.x, a4.y, a4.z, a4.w};
        const float c[4] = {b4.x, b4.y, b4.z, b4.w};
#pragma unroll
        for (int p = 0; p < 4; ++p)
#pragma unroll
            for (int q = 0; q < 4; ++q)
                acc[p][q] = __builtin_fmaf(a[p], c[q], acc[p][q]);
    }
    __syncthreads();

    for (int k = g; k < 67; k += 4) {
        const float* frow = features + ((size_t)b * CC + (64 + k - 3)) * NN;
        As[k][r] = frow[i0 + r];
        Bs[k][r] = frow[j0 + r];
    }
    __syncthreads();

    if (tid < 128) {
        const int rr = tid & 63;
        const float (*S)[64] = (tid < 64) ? As : Bs;
#pragma unroll
        for (int j = 0; j < 4; ++j)
#pragma unroll
            for (int l = 0; l < 8; ++l) {
                float x = S[8 * j + l][rr];
                ph[j][l] = fadd_(ph[j][l], fmul_(x, x));      // it = 2
            }
#pragma unroll
        for (int j = 0; j < 4; ++j)
#pragma unroll
            for (int l = 0; l < 8; ++l) {
                float x = S[32 + 8 * j + l][rr];
                ph[j][l] = fadd_(ph[j][l], fmul_(x, x));      // it = 3
            }
        float v[8];
#pragma unroll
        for (int l = 0; l < 8; ++l)
            v[l] = fadd_(fadd_(fadd_(ph[0][l], ph[1][l]), ph[2][l]), ph[3][l]);
        float h4_0 = fadd_(v[0], v[4]), h4_1 = fadd_(v[1], v[5]);
        float h4_2 = fadd_(v[2], v[6]), h4_3 = fadd_(v[3], v[7]);
        float h1 = fadd_(fadd_(h4_0, h4_2), fadd_(h4_1, h4_3));
        float t0 = S[64][rr], t1 = S[65][rr], t2 = S[66][rr];
        h1 = fadd_(h1, fmul_(t0, t0));
        h1 = fadd_(h1, fmul_(t1, t1));
        h1 = fadd_(h1, fmul_(t2, t2));
        if (tid < 64) s_aai[rr] = h1; else s_aaj[rr] = h1;
    }

#pragma unroll 4
    for (int kk = 0; kk < 67; ++kk) {
        float4 a4 = *(const float4*)&As[kk][4 * ty];
        float4 b4 = *(const float4*)&Bs[kk][4 * tx];
        const float a[4] = {a4.x, a4.y, a4.z, a4.w};
        const float c[4] = {b4.x, b4.y, b4.z, b4.w};
#pragma unroll
        for (int p = 0; p < 4; ++p)
#pragma unroll
            for (int q = 0; q < 4; ++q)
                acc[p][q] = __builtin_fmaf(a[p], c[q], acc[p][q]);
    }
    __syncthreads();

#pragma unroll
    for (int p = 0; p < 4; ++p) {
        const int i = i0 + 4 * ty + p;
        const float aai = s_aai[4 * ty + p];
        float4 o;
        o.x = __builtin_fmaf(-2.0f, acc[p][0], fadd_(aai, s_aaj[4 * tx + 0]));
        o.y = __builtin_fmaf(-2.0f, acc[p][1], fadd_(aai, s_aaj[4 * tx + 1]));
        o.z = __builtin_fmaf(-2.0f, acc[p][2], fadd_(aai, s_aaj[4 * tx + 2]));
        o.w = __builtin_fmaf(-2.0f, acc[p][3], fadd_(aai, s_aaj[4 * tx + 3]));
        *(float4*)&dist[((size_t)b * NN + i) * NN + j0 + 4 * tx] = o;
    }
}

// ---------------------------------------------------------------------------
// DPP wave64 argmax combine with first-occurrence index tiebreak.
// ---------------------------------------------------------------------------
template <int CTRL>
__device__ __forceinline__ void dpp_step(float& v, int& i) {
    int ovb = __builtin_amdgcn_update_dpp(0, __float_as_int(v), CTRL, 0xF, 0xF, false);
    int oi  = __builtin_amdgcn_update_dpp(0, i,                 CTRL, 0xF, 0xF, false);
    float ov = __int_as_float(ovb);
    if (ov > v || (ov == v && oi < i)) { v = ov; i = oi; }
}

// local (value, index) update, ascending-index visitation => first-occurrence
__device__ __forceinline__ void upd(float& bv, int& bi, float m, int idx) {
    if (m > bv) { bv = m; bi = idx; }
}

// chain merge with explicit index tiebreak (chains cover interleaved chunks)
__device__ __forceinline__ void cmb(float& bv, int& bi, float v, int i) {
    if (v > bv || (v == bv && i < bi)) { bv = v; bi = i; }
}

// ---------------------------------------------------------------------------
// Sequential FPS — R22: ONE wave (64 threads) per batch, 64 cols/thread.
// R19-R21 post-mortem: forcing load co-residency (asm loads, single vmcnt(0))
// changed nothing => step was already ~1 mem trip; cost is fixed serial
// latency: mem ~1100 + fmin/scan ~500 (exposed after full drain) + DPP ~150
// + cross-wave LDS/barrier combine ~300. R22 attacks all three:
//   (1) 1 wave => no barrier, no LDS combine; readlane(63) gives uniform last.
//   (2) counted partial drains (vmcnt 14,12,...,0) + sched_barrier(0) after
//       each (rule #18) => fmin/scan of chunk c runs DURING arrival of c+1..15.
//   (3) 4 interleaved scan chains (chunk c -> chain c&3), merged with
//       index-tiebreak comparator => 4x shorter serial chain, exact
//       first-occurrence argmax semantics preserved.
// Thread t, chunk c (c=0..15) covers global idx 256c + 4t + e. Chains visit
// ascending global index within themselves; cross-chain/cross-lane ties are
// resolved by explicit index compare (cmb/dpp_step). Confirming signals:
// VGPR_Count ~150 (16 load quads + 16 mind quads), Workgroup_Size 64.
// ---------------------------------------------------------------------------
#define CHUNK(c, dd, mm, BV, BI)                                               \
    mm[0] = fminf(mm[0], dd[0]); mm[1] = fminf(mm[1], dd[1]);                  \
    mm[2] = fminf(mm[2], dd[2]); mm[3] = fminf(mm[3], dd[3]);                  \
    upd(BV, BI, mm[0], 256 * c + t4 + 0);                                      \
    upd(BV, BI, mm[1], 256 * c + t4 + 1);                                      \
    upd(BV, BI, mm[2], 256 * c + t4 + 2);                                      \
    upd(BV, BI, mm[3], 256 * c + t4 + 3);

__global__ __launch_bounds__(64, 1) void fps_kernel(const float* __restrict__ dist,
                                                    int* __restrict__ out) {
    const int b = blockIdx.x;
    const int tid = threadIdx.x;          // 0..63, single wave
    const float* Dm = dist + (size_t)b * NN * NN;

    __shared__ int s_hist[NPOINT];

    f32x4 m0, m1, m2, m3, m4, m5, m6, m7, m8, m9, m10, m11, m12, m13, m14, m15;
    m0 = (f32x4)(1e10f);
    m1 = m0; m2 = m0; m3 = m0; m4 = m0; m5 = m0; m6 = m0; m7 = m0;
    m8 = m0; m9 = m0; m10 = m0; m11 = m0; m12 = m0; m13 = m0; m14 = m0; m15 = m0;

    int last = 0;
    const int t4 = 4 * tid;
    // loop-invariant byte voffsets; +offset: immediates cover +0/1/2/3 KiB
    const unsigned vb0 = 16u * tid;
    const unsigned vb1 = vb0 + 4096u;
    const unsigned vb2 = vb0 + 8192u;
    const unsigned vb3 = vb0 + 12288u;

    for (int k = 0; k < NPOINT; ++k) {
        const float* rowbase = Dm + (size_t)last * NN;   // uniform, SALU

        f32x4 d0, d1, d2, d3, d4, d5, d6, d7, d8, d9, d10, d11, d12, d13, d14, d15;
        asm volatile("global_load_dwordx4 %0, %1, %2"             : "=v"(d0)  : "v"(vb0), "s"(rowbase));
        asm volatile("global_load_dwordx4 %0, %1, %2 offset:1024" : "=v"(d1)  : "v"(vb0), "s"(rowbase));
        asm volatile("global_load_dwordx4 %0, %1, %2 offset:2048" : "=v"(d2)  : "v"(vb0), "s"(rowbase));
        asm volatile("global_load_dwordx4 %0, %1, %2 offset:3072" : "=v"(d3)  : "v"(vb0), "s"(rowbase));
        asm volatile("global_load_dwordx4 %0, %1, %2"             : "=v"(d4)  : "v"(vb1), "s"(rowbase));
        asm volatile("global_load_dwordx4 %0, %1, %2 offset:1024" : "=v"(d5)  : "v"(vb1), "s"(rowbase));
        asm volatile("global_load_dwordx4 %0, %1, %2 offset:2048" : "=v"(d6)  : "v"(vb1), "s"(rowbase));
        asm volatile("global_load_dwordx4 %0, %1, %2 offset:3072" : "=v"(d7)  : "v"(vb1), "s"(rowbase));
        asm volatile("global_load_dwordx4 %0, %1, %2"             : "=v"(d8)  : "v"(vb2), "s"(rowbase));
        asm volatile("global_load_dwordx4 %0, %1, %2 offset:1024" : "=v"(d9)  : "v"(vb2), "s"(rowbase));
        asm volatile("global_load_dwordx4 %0, %1, %2 offset:2048" : "=v"(d10) : "v"(vb2), "s"(rowbase));
        asm volatile("global_load_dwordx4 %0, %1, %2 offset:3072" : "=v"(d11) : "v"(vb2), "s"(rowbase));
        asm volatile("global_load_dwordx4 %0, %1, %2"             : "=v"(d12) : "v"(vb3), "s"(rowbase));
        asm volatile("global_load_dwordx4 %0, %1, %2 offset:1024" : "=v"(d13) : "v"(vb3), "s"(rowbase));
        asm volatile("global_load_dwordx4 %0, %1, %2 offset:2048" : "=v"(d14) : "v"(vb3), "s"(rowbase));
        asm volatile("global_load_dwordx4 %0, %1, %2 offset:3072" : "=v"(d15) : "v"(vb3), "s"(rowbase));

        if (tid == 0) s_hist[k] = last;   // ds_write, overlaps load latency

        float bv0 = -1e30f, bv1 = -1e30f, bv2 = -1e30f, bv3 = -1e30f;
        int   bi0 = 0, bi1 = 0, bi2 = 0, bi3 = 0;

        asm volatile("s_waitcnt vmcnt(14)" ::: "memory");
        __builtin_amdgcn_sched_barrier(0);
        CHUNK(0, d0, m0, bv0, bi0)
        CHUNK(1, d1, m1, bv1, bi1)
        asm volatile("s_waitcnt vmcnt(12)" ::: "memory");
        __builtin_amdgcn_sched_barrier(0);
        CHUNK(2, d2, m2, bv2, bi2)
        CHUNK(3, d3, m3, bv3, bi3)
        asm volatile("s_waitcnt vmcnt(10)" ::: "memory");
        __builtin_amdgcn_sched_barrier(0);
        CHUNK(4, d4, m4, bv0, bi0)
        CHUNK(5, d5, m5, bv1, bi1)
        asm volatile("s_waitcnt vmcnt(8)" ::: "memory");
        __builtin_amdgcn_sched_barrier(0);
        CHUNK(6, d6, m6, bv2, bi2)
        CHUNK(7, d7, m7, bv3, bi3)
        asm volatile("s_waitcnt vmcnt(6)" ::: "memory");
        __builtin_amdgcn_sched_barrier(0);
        CHUNK(8, d8, m8, bv0, bi0)
        CHUNK(9, d9, m9, bv1, bi1)
        asm volatile("s_waitcnt vmcnt(4)" ::: "memory");
        __builtin_amdgcn_sched_barrier(0);
        CHUNK(10, d10, m10, bv2, bi2)
        CHUNK(11, d11, m11, bv3, bi3)
        asm volatile("s_waitcnt vmcnt(2)" ::: "memory");
        __builtin_amdgcn_sched_barrier(0);
        CHUNK(12, d12, m12, bv0, bi0)
        CHUNK(13, d13, m13, bv1, bi1)
        asm volatile("s_waitcnt vmcnt(0)" ::: "memory");
        __builtin_amdgcn_sched_barrier(0);
        CHUNK(14, d14, m14, bv2, bi2)
        CHUNK(15, d15, m15, bv3, bi3)

        // merge 4 chains (index tiebreak => exact first-occurrence)
        cmb(bv0, bi0, bv1, bi1);
        cmb(bv2, bi2, bv3, bi3);
        cmb(bv0, bi0, bv2, bi2);

        // wave64 DPP argmax -> lane 63, readlane => uniform
        dpp_step<0xB1>(bv0, bi0);    // quad_perm [1,0,3,2]  (xor 1)
        dpp_step<0x4E>(bv0, bi0);    // quad_perm [2,3,0,1]  (xor 2)
        dpp_step<0x141>(bv0, bi0);   // row_half_mirror      (xor 4)
        dpp_step<0x140>(bv0, bi0);   // row_mirror           (xor 8)
        dpp_step<0x142>(bv0, bi0);   // row_bcast15
        dpp_step<0x143>(bv0, bi0);   // row_bcast31
        last = __builtin_amdgcn_readlane(bi0, 63);
    }

    // flush history: 16 ints per lane, coalesced (single wave, no barrier)
#pragma unroll
    for (int c = 0; c < 16; ++c)
        out[b * NPOINT + 64 * c + tid] = s_hist[64 * c + tid];
}

// ---------------------------------------------------------------------------
extern "C" void kernel_launch(void* const* d_in, const int* in_sizes, int n_in,
                              void* d_out, int out_size, void* d_ws, size_t ws_size,
                              hipStream_t stream) {
    const float* points   = (const float*)d_in[0];
    const float* features = (const float*)d_in[1];
    int* out = (int*)d_out;

    float* dist = (float*)d_ws;   // exactly 256 MiB

    dim3 g(NN / 64, NN / 64, BB);
    dist_kernel<<<g, 256, 0, stream>>>(points, features, dist);

    fps_kernel<<<BB, 64, 0, stream>>>(dist, out);
}